// Round 10
// baseline (206.627 us; speedup 1.0000x reference)
//
#include <hip/hip_runtime.h>
#include <hip/hip_bf16.h>

#define EDIM 1024
#define NH   16
#define DH   64
#define BB   2
#define SS   2048
#define MM   (BB*SS)   // 4096 rows

typedef unsigned short u16;
typedef unsigned int   u32;
typedef __attribute__((ext_vector_type(4)))  float f32x4;
typedef __attribute__((ext_vector_type(16))) float f32x16;
typedef __attribute__((ext_vector_type(8)))  short s16x8;

__device__ __forceinline__ u16 f2bf(float x) {
    __hip_bfloat16 b = __float2bfloat16(x);   // RNE; native cvt
    return *(u16*)&b;
}
__device__ __forceinline__ u32 cvtpk(float lo, float hi_) {
    u32 r;
    asm("v_cvt_pk_bf16_f32 %0, %1, %2" : "=v"(r) : "v"(lo), "v"(hi_));
    return r;   // low16 = bf16(lo), high16 = bf16(hi_)
}
// v_permlane32_swap_b32: vdst.row1 <-> vsrc.row0 (rows = 32-lane halves)
__device__ __forceinline__ void swap32(u32& a, u32& b) {
    asm("v_permlane32_swap_b32 %0, %1" : "+v"(a), "+v"(b));
}

// async 16B global -> LDS (dest = wave-uniform base + lane*16)
__device__ __forceinline__ void gload16(const void* g, void* l) {
    __builtin_amdgcn_global_load_lds(
        (const __attribute__((address_space(1))) unsigned int*)g,
        (__attribute__((address_space(3))) unsigned int*)l, 16, 0, 0);
}

// ---------------------------------------------------------------------------
// One-shot fp32 -> bf16 conversion of x, Wq|Wk|Wv (concat), Wo.
// ---------------------------------------------------------------------------
__global__ __launch_bounds__(256) void convert_all(const float* __restrict__ x,
                                                   const float* __restrict__ Wq,
                                                   const float* __restrict__ Wk,
                                                   const float* __restrict__ Wv,
                                                   const float* __restrict__ Wo,
                                                   u16* __restrict__ xh,
                                                   u16* __restrict__ wqkv,
                                                   u16* __restrict__ woh)
{
    const int i = blockIdx.x * 256 + threadIdx.x;
    const float* src; ushort4* dst; int off;
    if (i < 1048576)      { src = x;  dst = (ushort4*)xh;   off = i; }
    else if (i < 1310720) { src = Wq; dst = (ushort4*)wqkv; off = i - 1048576; }
    else if (i < 1572864) { src = Wk; dst = (ushort4*)wqkv; off = i - 1310720 + 262144; }
    else if (i < 1835008) { src = Wv; dst = (ushort4*)wqkv; off = i - 1572864 + 524288; }
    else                  { src = Wo; dst = (ushort4*)woh;  off = i - 1835008; }
    const int so = (i < 1048576) ? i
                 : (i < 1310720) ? (i - 1048576)
                 : (i < 1572864) ? (i - 1310720)
                 : (i < 1835008) ? (i - 1572864) : (i - 1835008);
    const float4 v = ((const float4*)src)[so];
    ushort4 h;
    h.x = f2bf(v.x); h.y = f2bf(v.y); h.z = f2bf(v.z); h.w = f2bf(v.w);
    dst[off] = h;
}

// ---------------------------------------------------------------------------
// Fused QKV GEMM: C[4096, 3072] = xh @ wqkv^T + bias,  K = 1024.
// 128x128 tile, BK=64, single-buffered 32 KB LDS, 2-barrier loop (m97
// structure; measured at this shape's structural ceiling ~480 TF).
// n in [0,1024) -> q [B,H,S,Dh]; [1024,2048) -> k; [2048,3072) -> vT.
// ---------------------------------------------------------------------------
__global__ __launch_bounds__(256) void gemm_qkv(const u16* __restrict__ A,
                                                const u16* __restrict__ B,
                                                const float* __restrict__ bq,
                                                const float* __restrict__ bk,
                                                const float* __restrict__ bv,
                                                u16* __restrict__ qb,
                                                u16* __restrict__ kb,
                                                u16* __restrict__ vT)
{
    __shared__ __align__(16) u16 As[128][64];   // 16 KB
    __shared__ __align__(16) u16 Bs[128][64];   // 16 KB

    const int tid  = threadIdx.x;
    const int lane = tid & 63, wid = tid >> 6;
    const int wm = wid >> 1, wn = wid & 1;
    const int swz = (blockIdx.x & 7) * 96 + (blockIdx.x >> 3);  // 768 blocks
    const int m0 = (swz & 31) * 128;
    const int n0 = (swz >> 5) * 128;

    // per-thread staging source offsets (bytes), hoisted out of the K-loop
    size_t aoff[4], boff[4];
    #pragma unroll
    for (int i = 0; i < 4; ++i) {
        const int flat = i * 256 + tid;
        const int row = flat >> 3, u = flat & 7;
        const size_t o = (size_t)row * 2048 + ((u ^ (row & 7)) << 4);
        aoff[i] = o; boff[i] = o;
    }
    const char* Abase = (const char*)(A + (size_t)m0 * 1024);
    const char* Bbase = (const char*)(B + (size_t)n0 * 1024);

    f32x4 acc[4][4];
    #pragma unroll
    for (int i = 0; i < 4; ++i)
        #pragma unroll
        for (int j = 0; j < 4; ++j) acc[i][j] = f32x4{0.f, 0.f, 0.f, 0.f};

    #pragma unroll 1
    for (int t = 0; t < 16; ++t) {
        const size_t kb_ = (size_t)t * 128;   // k0*2 bytes
        #pragma unroll
        for (int i = 0; i < 4; ++i)
            gload16(Abase + aoff[i] + kb_, (char*)As + (i * 256 + wid * 64) * 16);
        #pragma unroll
        for (int i = 0; i < 4; ++i)
            gload16(Bbase + boff[i] + kb_, (char*)Bs + (i * 256 + wid * 64) * 16);
        __syncthreads();

        #pragma unroll
        for (int kk = 0; kk < 2; ++kk) {
            s16x8 af[4], bfr[4];
            #pragma unroll
            for (int i = 0; i < 4; ++i) {
                const int rowA = wm * 64 + i * 16 + (lane & 15);
                af[i] = *(const s16x8*)((const char*)As + rowA * 128 + (((kk * 4 + (lane >> 4)) ^ (rowA & 7)) << 4));
                const int rowB = wn * 64 + i * 16 + (lane & 15);
                bfr[i] = *(const s16x8*)((const char*)Bs + rowB * 128 + (((kk * 4 + (lane >> 4)) ^ (rowB & 7)) << 4));
            }
            #pragma unroll
            for (int i = 0; i < 4; ++i)
                #pragma unroll
                for (int j = 0; j < 4; ++j)
                    acc[i][j] = __builtin_amdgcn_mfma_f32_16x16x32_bf16(af[i], bfr[j], acc[i][j], 0, 0, 0);
        }
        __syncthreads();   // LDS reads done before next stage overwrites
    }

    // epilogue: branch is block-uniform (n0 multiple of 128)
    if (n0 < 1024) {
        #pragma unroll
        for (int i = 0; i < 4; ++i) {
            const int mbase = m0 + wm * 64 + i * 16 + ((lane >> 4) * 4);
            #pragma unroll
            for (int j = 0; j < 4; ++j) {
                const int n = n0 + wn * 64 + j * 16 + (lane & 15);
                const float bias = bq[n];
                const int h_ = n >> 6, d_ = n & 63;
                #pragma unroll
                for (int r = 0; r < 4; ++r) {
                    const int m = mbase + r;
                    const int b_ = m >> 11, s_ = m & 2047;
                    qb[((size_t)(b_ * NH + h_) * SS + s_) * DH + d_] = f2bf(acc[i][j][r] + bias);
                }
            }
        }
    } else if (n0 < 2048) {
        #pragma unroll
        for (int i = 0; i < 4; ++i) {
            const int mbase = m0 + wm * 64 + i * 16 + ((lane >> 4) * 4);
            #pragma unroll
            for (int j = 0; j < 4; ++j) {
                const int n = n0 + wn * 64 + j * 16 + (lane & 15);
                const float bias = bk[n - 1024];
                const int h_ = (n >> 6) & 15, d_ = n & 63;
                #pragma unroll
                for (int r = 0; r < 4; ++r) {
                    const int m = mbase + r;
                    const int b_ = m >> 11, s_ = m & 2047;
                    kb[((size_t)(b_ * NH + h_) * SS + s_) * DH + d_] = f2bf(acc[i][j][r] + bias);
                }
            }
        }
    } else {
        #pragma unroll
        for (int i = 0; i < 4; ++i) {
            const int mbase = m0 + wm * 64 + i * 16 + ((lane >> 4) * 4);
            #pragma unroll
            for (int j = 0; j < 4; ++j) {
                const int n = n0 + wn * 64 + j * 16 + (lane & 15);
                const float bias = bv[n - 2048];
                const int hd = n - 2048;
                #pragma unroll
                for (int r = 0; r < 4; ++r) {
                    const int m = mbase + r;
                    const int b_ = m >> 11, s_ = m & 2047;
                    vT[((size_t)(b_ * EDIM) + hd) * SS + s_] = f2bf(acc[i][j][r] + bias);
                }
            }
        }
    }
}

// ---------------------------------------------------------------------------
// Output GEMM: out[4096,1024] = valsh @ woh^T + bo, fp32 out. K = 1024.
// 64x128 tile, BK=64, single-buffered 24 KB LDS, 2-barrier loop, swizzled.
// ---------------------------------------------------------------------------
__global__ __launch_bounds__(256) void gemm_out(const u16* __restrict__ A,
                                                const u16* __restrict__ B,
                                                const float* __restrict__ bo,
                                                float* __restrict__ out)
{
    __shared__ __align__(16) u16 As[64][64];     // 8 KB
    __shared__ __align__(16) u16 Bs[128][64];    // 16 KB

    const int tid  = threadIdx.x;
    const int lane = tid & 63, wid = tid >> 6;
    const int wm = wid >> 1, wn = wid & 1;
    const int swz = (blockIdx.x & 7) * 64 + (blockIdx.x >> 3);   // 512 blocks
    const int m0 = (swz & 63) * 64;
    const int n0 = (swz >> 6) * 128;

    size_t aoff[2], boff[4];
    #pragma unroll
    for (int i = 0; i < 2; ++i) {
        const int flat = i * 256 + tid;
        const int row = flat >> 3, u = flat & 7;
        aoff[i] = (size_t)row * 2048 + ((u ^ (row & 7)) << 4);
    }
    #pragma unroll
    for (int i = 0; i < 4; ++i) {
        const int flat = i * 256 + tid;
        const int row = flat >> 3, u = flat & 7;
        boff[i] = (size_t)row * 2048 + ((u ^ (row & 7)) << 4);
    }
    const char* Abase = (const char*)(A + (size_t)m0 * 1024);
    const char* Bbase = (const char*)(B + (size_t)n0 * 1024);

    f32x4 acc[2][4];
    #pragma unroll
    for (int i = 0; i < 2; ++i)
        #pragma unroll
        for (int j = 0; j < 4; ++j) acc[i][j] = f32x4{0.f, 0.f, 0.f, 0.f};

    #pragma unroll 1
    for (int t = 0; t < 16; ++t) {
        const size_t kb_ = (size_t)t * 128;
        #pragma unroll
        for (int i = 0; i < 2; ++i)
            gload16(Abase + aoff[i] + kb_, (char*)As + (i * 256 + wid * 64) * 16);
        #pragma unroll
        for (int i = 0; i < 4; ++i)
            gload16(Bbase + boff[i] + kb_, (char*)Bs + (i * 256 + wid * 64) * 16);
        __syncthreads();

        #pragma unroll
        for (int kk = 0; kk < 2; ++kk) {
            s16x8 af[2], bfr[4];
            #pragma unroll
            for (int i = 0; i < 2; ++i) {
                const int rowA = wm * 32 + i * 16 + (lane & 15);
                af[i] = *(const s16x8*)((const char*)As + rowA * 128 + (((kk * 4 + (lane >> 4)) ^ (rowA & 7)) << 4));
            }
            #pragma unroll
            for (int j = 0; j < 4; ++j) {
                const int rowB = wn * 64 + j * 16 + (lane & 15);
                bfr[j] = *(const s16x8*)((const char*)Bs + rowB * 128 + (((kk * 4 + (lane >> 4)) ^ (rowB & 7)) << 4));
            }
            #pragma unroll
            for (int i = 0; i < 2; ++i)
                #pragma unroll
                for (int j = 0; j < 4; ++j)
                    acc[i][j] = __builtin_amdgcn_mfma_f32_16x16x32_bf16(af[i], bfr[j], acc[i][j], 0, 0, 0);
        }
        __syncthreads();
    }

    #pragma unroll
    for (int i = 0; i < 2; ++i) {
        const int mbase = m0 + wm * 32 + i * 16 + ((lane >> 4) * 4);
        #pragma unroll
        for (int j = 0; j < 4; ++j) {
            const int n = n0 + wn * 64 + j * 16 + (lane & 15);
            #pragma unroll
            for (int r = 0; r < 4; ++r)
                out[(size_t)(mbase + r) * EDIM + n] = acc[i][j][r] + bo[n];
        }
    }
}

// ---------------------------------------------------------------------------
// MFMA flash attention, swapped-QK^T, in-register softmax (T12), dbuf K/V.
// ROUND 10 changes:
//  - kt swizzle upgraded: swz_k(row) = (row&7) ^ ((row>>3)&3) — the 4 lanes
//    {l,l+8,l+16,l+24} sharing (row&7) now hit 4 distinct bank groups
//    (was a 4-way conflict, 2.1M conflict-cycles in r9).
//  - vt swizzle upgraded: swz_v(row) = (row&15) ^ ((row&16)>>2) — rows ±16
//    split by XOR 4; residual u<->u^8 aliasing is inherent 2-way (free).
//  - setprio removed: kb-chains are fully unrolled and independent; the
//    builtin fenced the scheduler and blocked MFMA(kb+1) ∥ softmax(kb).
// ---------------------------------------------------------------------------
__global__ __launch_bounds__(256) void attn_mfma(const u16* __restrict__ q,
                                                 const u16* __restrict__ k,
                                                 const u16* __restrict__ vT,
                                                 u16* __restrict__ valsh)
{
    __shared__ __align__(16) u16 kt[2][128][64];    // 32 KB
    __shared__ __align__(16) u16 vt[2][64][128];    // 32 KB

    const int tid = threadIdx.x, lane = tid & 63, wid = tid >> 6;
    const int lq = lane & 31, hi = lane >> 5;
    const int swz = (blockIdx.x & 7) * 64 + (blockIdx.x >> 3);   // 512 blocks
    const int bh = swz >> 4, qt = swz & 15;
    const int b = bh >> 4, h = bh & 15;

    // ---- Q B-frags straight from global (L2-resident, one-time) ----
    const u16* qg = q + ((size_t)bh * SS + qt * 128 + wid * 32 + lq) * DH + hi * 8;
    s16x8 qf[4];
    #pragma unroll
    for (int ks = 0; ks < 4; ++ks) qf[ks] = *(const s16x8*)(qg + ks * 16);

    f32x16 acc_o[2];
    #pragma unroll
    for (int db = 0; db < 2; ++db)
        #pragma unroll
        for (int r = 0; r < 16; ++r) acc_o[db][r] = 0.f;
    float rs = 0.f;

    const char* kbh = (const char*)(k + (size_t)bh * SS * DH);
    const char* vbh = (const char*)(vT + ((size_t)b * EDIM + h * DH) * SS);

    auto stage = [&](int buf, int c0) {
        #pragma unroll
        for (int i = 0; i < 4; ++i) {
            const int flat = i * 256 + tid;
            const int row = flat >> 3, u = flat & 7;
            const int su = u ^ (row & 7) ^ ((row >> 3) & 3);
            gload16(kbh + (size_t)(c0 + row) * 128 + (su << 4),
                    (char*)kt + buf * 16384 + (i * 256 + wid * 64) * 16);
        }
        #pragma unroll
        for (int i = 0; i < 4; ++i) {
            const int flat = i * 256 + tid;
            const int row = flat >> 4, u = flat & 15;
            const int su = u ^ (row & 15) ^ ((row & 16) >> 2);
            gload16(vbh + (size_t)row * (SS * 2) + (size_t)c0 * 2 + (su << 4),
                    (char*)vt + buf * 16384 + (i * 256 + wid * 64) * 16);
        }
    };

    stage(0, 0);
    __syncthreads();

    int buf = 0;
    #pragma unroll 1
    for (int c = 0; c < 16; ++c) {
        if (c < 15) stage(buf ^ 1, (c + 1) * 128);   // prefetch next chunk
        const char* ktb = (const char*)kt + buf * 16384;
        const char* vtb = (const char*)vt + buf * 16384;

        #pragma unroll
        for (int kb = 0; kb < 4; ++kb) {
            // ---- S^T = K @ Q^T over d (4 k-steps of 16) ----
            f32x16 sc;
            #pragma unroll
            for (int r = 0; r < 16; ++r) sc[r] = 0.f;
            const int krow = kb * 32 + lq;
            #pragma unroll
            for (int ks = 0; ks < 4; ++ks) {
                const int u = (ks * 2 + hi) ^ (krow & 7) ^ ((krow >> 3) & 3);
                const s16x8 kf = *(const s16x8*)(ktb + krow * 128 + u * 16);
                sc = __builtin_amdgcn_mfma_f32_32x32x16_bf16(kf, qf[ks], sc, 0, 0, 0);
            }

            // ---- P = exp(S/64) in-register; accumulate rowsum ----
            #pragma unroll
            for (int r = 0; r < 16; ++r) {
                sc[r] = __builtin_amdgcn_exp2f(sc[r] * 0.0225421209f);  // log2(e)/64
                rs += sc[r];
            }

            // ---- pack to PV A-frags: cvt_pk pairs + permlane32_swap ----
            u32 w0 = cvtpk(sc[0],  sc[1]),  w1 = cvtpk(sc[2],  sc[3]);
            u32 w2 = cvtpk(sc[4],  sc[5]),  w3 = cvtpk(sc[6],  sc[7]);
            u32 w4 = cvtpk(sc[8],  sc[9]),  w5 = cvtpk(sc[10], sc[11]);
            u32 w6 = cvtpk(sc[12], sc[13]), w7 = cvtpk(sc[14], sc[15]);
            swap32(w0, w2);
            swap32(w1, w3);
            swap32(w4, w6);
            swap32(w5, w7);
            union { u32 w[4]; s16x8 v; } pa0, pa1;
            pa0.w[0] = w0; pa0.w[1] = w1; pa0.w[2] = w2; pa0.w[3] = w3;
            pa1.w[0] = w4; pa1.w[1] = w5; pa1.w[2] = w6; pa1.w[3] = w7;

            // ---- O += P @ V : A = P frags (reg), B = V^T rows from LDS ----
            #pragma unroll
            for (int t = 0; t < 2; ++t) {
                const s16x8 pat = t ? pa1.v : pa0.v;
                const int kst = kb * 2 + t;
                #pragma unroll
                for (int db = 0; db < 2; ++db) {
                    const int vrow = db * 32 + lq;
                    const int u = (kst * 2 + hi) ^ (vrow & 15) ^ ((vrow & 16) >> 2);
                    const s16x8 vf = *(const s16x8*)(vtb + vrow * 256 + u * 16);
                    acc_o[db] = __builtin_amdgcn_mfma_f32_32x32x16_bf16(pat, vf, acc_o[db], 0, 0, 0);
                }
            }
        }
        __syncthreads();   // staged next chunk visible; this chunk's reads done
        buf ^= 1;
    }

    // ---- rowsum: lane l and l^32 hold complementary key sets of q=lq ----
    const float rsf = rs + __shfl_xor(rs, 32, 64);
    const float inv = 1.f / rsf;
    float iv[16];
    #pragma unroll
    for (int r = 0; r < 16; ++r)
        iv[r] = __shfl(inv, (r & 3) + 8 * (r >> 2) + 4 * hi, 64);

    // ---- epilogue: normalize + write bf16 vals [B*S][E] ----
    #pragma unroll
    for (int db = 0; db < 2; ++db)
        #pragma unroll
        for (int r = 0; r < 16; ++r) {
            const int srow = qt * 128 + wid * 32 + (r & 3) + 8 * (r >> 2) + 4 * hi;
            const int col  = h * 64 + db * 32 + lq;
            valsh[(size_t)(b * SS + srow) * EDIM + col] = f2bf(acc_o[db][r] * iv[r]);
        }
}

// ---------------------------------------------------------------------------
extern "C" void kernel_launch(void* const* d_in, const int* in_sizes, int n_in,
                              void* d_out, int out_size, void* d_ws, size_t ws_size,
                              hipStream_t stream)
{
    const float* x  = (const float*)d_in[0];
    const float* Wq = (const float*)d_in[1];
    const float* bq = (const float*)d_in[2];
    const float* Wk = (const float*)d_in[3];
    const float* bk = (const float*)d_in[4];
    const float* Wv = (const float*)d_in[5];
    const float* bv = (const float*)d_in[6];
    const float* Wo = (const float*)d_in[7];
    const float* bo = (const float*)d_in[8];
    float* out = (float*)d_out;

    u16* W = (u16*)d_ws;
    const size_t M1 = 1024 * 1024;
    u16* xh    = W;                 // [4096][1024]        4M elems
    u16* wqkv  = W + 4  * M1;       // [3072][1024]        3M
    u16* woh   = W + 7  * M1;       // [1024][1024]        1M
    u16* qbuf  = W + 8  * M1;       // [BH][S][64]         4M
    u16* kbuf  = W + 12 * M1;       // [BH][S][64]         4M
    u16* vbufT = W + 16 * M1;       // [B*1024][S]         4M
    u16* valsh = W + 20 * M1;       // [4096][1024]        4M

    convert_all<<<dim3(8192), 256, 0, stream>>>(x, Wq, Wk, Wv, Wo, xh, wqkv, woh);

    gemm_qkv<<<dim3(768), 256, 0, stream>>>(xh, wqkv, bq, bk, bv, qbuf, kbuf, vbufT);

    attn_mfma<<<dim3(BB * NH * (SS / 128)), 256, 0, stream>>>(qbuf, kbuf, vbufT, valsh);

    gemm_out<<<dim3(512), 256, 0, stream>>>(valsh, woh, bo, out);
}

// Round 11
// 200.002 us; speedup vs baseline: 1.0331x; 1.0331x over previous
//
#include <hip/hip_runtime.h>
#include <hip/hip_bf16.h>

#define EDIM 1024
#define NH   16
#define DH   64
#define BB   2
#define SS   2048
#define MM   (BB*SS)   // 4096 rows

typedef unsigned short u16;
typedef unsigned int   u32;
typedef __attribute__((ext_vector_type(4)))  float f32x4;
typedef __attribute__((ext_vector_type(16))) float f32x16;
typedef __attribute__((ext_vector_type(8)))  short s16x8;

__device__ __forceinline__ u16 f2bf(float x) {
    __hip_bfloat16 b = __float2bfloat16(x);   // RNE; native cvt
    return *(u16*)&b;
}
__device__ __forceinline__ u32 cvtpk(float lo, float hi_) {
    u32 r;
    asm("v_cvt_pk_bf16_f32 %0, %1, %2" : "=v"(r) : "v"(lo), "v"(hi_));
    return r;   // low16 = bf16(lo), high16 = bf16(hi_)
}
// v_permlane32_swap_b32: vdst.row1 <-> vsrc.row0 (rows = 32-lane halves)
__device__ __forceinline__ void swap32(u32& a, u32& b) {
    asm("v_permlane32_swap_b32 %0, %1" : "+v"(a), "+v"(b));
}

// async 16B global -> LDS (dest = wave-uniform base + lane*16)
__device__ __forceinline__ void gload16(const void* g, void* l) {
    __builtin_amdgcn_global_load_lds(
        (const __attribute__((address_space(1))) unsigned int*)g,
        (__attribute__((address_space(3))) unsigned int*)l, 16, 0, 0);
}

// log2(e)/64 — folded into Q at projection time (softmax scale)
#define QSCALE 0.0225421209f

// ---------------------------------------------------------------------------
// One-shot fp32 -> bf16 conversion of x, Wq|Wk|Wv (concat), Wo.
// ---------------------------------------------------------------------------
__global__ __launch_bounds__(256) void convert_all(const float* __restrict__ x,
                                                   const float* __restrict__ Wq,
                                                   const float* __restrict__ Wk,
                                                   const float* __restrict__ Wv,
                                                   const float* __restrict__ Wo,
                                                   u16* __restrict__ xh,
                                                   u16* __restrict__ wqkv,
                                                   u16* __restrict__ woh)
{
    const int i = blockIdx.x * 256 + threadIdx.x;
    const float* src; ushort4* dst; int off;
    if (i < 1048576)      { src = x;  dst = (ushort4*)xh;   off = i; }
    else if (i < 1310720) { src = Wq; dst = (ushort4*)wqkv; off = i - 1048576; }
    else if (i < 1572864) { src = Wk; dst = (ushort4*)wqkv; off = i - 1310720 + 262144; }
    else if (i < 1835008) { src = Wv; dst = (ushort4*)wqkv; off = i - 1572864 + 524288; }
    else                  { src = Wo; dst = (ushort4*)woh;  off = i - 1835008; }
    const int so = (i < 1048576) ? i
                 : (i < 1310720) ? (i - 1048576)
                 : (i < 1572864) ? (i - 1310720)
                 : (i < 1835008) ? (i - 1572864) : (i - 1835008);
    const float4 v = ((const float4*)src)[so];
    ushort4 h;
    h.x = f2bf(v.x); h.y = f2bf(v.y); h.z = f2bf(v.z); h.w = f2bf(v.w);
    dst[off] = h;
}

// ---------------------------------------------------------------------------
// Fused QKV GEMM: C[4096, 3072] = xh @ wqkv^T + bias,  K = 1024.
// 128x128 tile, BK=64, single-buffered 32 KB LDS, 2-barrier loop.
// n in [0,1024) -> q [B,H,S,Dh] * QSCALE (softmax scale folded in);
// [1024,2048) -> k; [2048,3072) -> vT.
// ---------------------------------------------------------------------------
__global__ __launch_bounds__(256) void gemm_qkv(const u16* __restrict__ A,
                                                const u16* __restrict__ B,
                                                const float* __restrict__ bq,
                                                const float* __restrict__ bk,
                                                const float* __restrict__ bv,
                                                u16* __restrict__ qb,
                                                u16* __restrict__ kb,
                                                u16* __restrict__ vT)
{
    __shared__ __align__(16) u16 As[128][64];   // 16 KB
    __shared__ __align__(16) u16 Bs[128][64];   // 16 KB

    const int tid  = threadIdx.x;
    const int lane = tid & 63, wid = tid >> 6;
    const int wm = wid >> 1, wn = wid & 1;
    const int swz = (blockIdx.x & 7) * 96 + (blockIdx.x >> 3);  // 768 blocks
    const int m0 = (swz & 31) * 128;
    const int n0 = (swz >> 5) * 128;

    size_t aoff[4], boff[4];
    #pragma unroll
    for (int i = 0; i < 4; ++i) {
        const int flat = i * 256 + tid;
        const int row = flat >> 3, u = flat & 7;
        const size_t o = (size_t)row * 2048 + ((u ^ (row & 7)) << 4);
        aoff[i] = o; boff[i] = o;
    }
    const char* Abase = (const char*)(A + (size_t)m0 * 1024);
    const char* Bbase = (const char*)(B + (size_t)n0 * 1024);

    f32x4 acc[4][4];
    #pragma unroll
    for (int i = 0; i < 4; ++i)
        #pragma unroll
        for (int j = 0; j < 4; ++j) acc[i][j] = f32x4{0.f, 0.f, 0.f, 0.f};

    #pragma unroll 1
    for (int t = 0; t < 16; ++t) {
        const size_t kb_ = (size_t)t * 128;   // k0*2 bytes
        #pragma unroll
        for (int i = 0; i < 4; ++i)
            gload16(Abase + aoff[i] + kb_, (char*)As + (i * 256 + wid * 64) * 16);
        #pragma unroll
        for (int i = 0; i < 4; ++i)
            gload16(Bbase + boff[i] + kb_, (char*)Bs + (i * 256 + wid * 64) * 16);
        __syncthreads();

        #pragma unroll
        for (int kk = 0; kk < 2; ++kk) {
            s16x8 af[4], bfr[4];
            #pragma unroll
            for (int i = 0; i < 4; ++i) {
                const int rowA = wm * 64 + i * 16 + (lane & 15);
                af[i] = *(const s16x8*)((const char*)As + rowA * 128 + (((kk * 4 + (lane >> 4)) ^ (rowA & 7)) << 4));
                const int rowB = wn * 64 + i * 16 + (lane & 15);
                bfr[i] = *(const s16x8*)((const char*)Bs + rowB * 128 + (((kk * 4 + (lane >> 4)) ^ (rowB & 7)) << 4));
            }
            #pragma unroll
            for (int i = 0; i < 4; ++i)
                #pragma unroll
                for (int j = 0; j < 4; ++j)
                    acc[i][j] = __builtin_amdgcn_mfma_f32_16x16x32_bf16(af[i], bfr[j], acc[i][j], 0, 0, 0);
        }
        __syncthreads();   // LDS reads done before next stage overwrites
    }

    // epilogue: branch is block-uniform (n0 multiple of 128)
    if (n0 < 1024) {
        #pragma unroll
        for (int i = 0; i < 4; ++i) {
            const int mbase = m0 + wm * 64 + i * 16 + ((lane >> 4) * 4);
            #pragma unroll
            for (int j = 0; j < 4; ++j) {
                const int n = n0 + wn * 64 + j * 16 + (lane & 15);
                const float bias = bq[n];
                const int h_ = n >> 6, d_ = n & 63;
                #pragma unroll
                for (int r = 0; r < 4; ++r) {
                    const int m = mbase + r;
                    const int b_ = m >> 11, s_ = m & 2047;
                    qb[((size_t)(b_ * NH + h_) * SS + s_) * DH + d_] =
                        f2bf((acc[i][j][r] + bias) * QSCALE);
                }
            }
        }
    } else if (n0 < 2048) {
        #pragma unroll
        for (int i = 0; i < 4; ++i) {
            const int mbase = m0 + wm * 64 + i * 16 + ((lane >> 4) * 4);
            #pragma unroll
            for (int j = 0; j < 4; ++j) {
                const int n = n0 + wn * 64 + j * 16 + (lane & 15);
                const float bias = bk[n - 1024];
                const int h_ = (n >> 6) & 15, d_ = n & 63;
                #pragma unroll
                for (int r = 0; r < 4; ++r) {
                    const int m = mbase + r;
                    const int b_ = m >> 11, s_ = m & 2047;
                    kb[((size_t)(b_ * NH + h_) * SS + s_) * DH + d_] = f2bf(acc[i][j][r] + bias);
                }
            }
        }
    } else {
        #pragma unroll
        for (int i = 0; i < 4; ++i) {
            const int mbase = m0 + wm * 64 + i * 16 + ((lane >> 4) * 4);
            #pragma unroll
            for (int j = 0; j < 4; ++j) {
                const int n = n0 + wn * 64 + j * 16 + (lane & 15);
                const float bias = bv[n - 2048];
                const int hd = n - 2048;
                #pragma unroll
                for (int r = 0; r < 4; ++r) {
                    const int m = mbase + r;
                    const int b_ = m >> 11, s_ = m & 2047;
                    vT[((size_t)(b_ * EDIM) + hd) * SS + s_] = f2bf(acc[i][j][r] + bias);
                }
            }
        }
    }
}

// ---------------------------------------------------------------------------
// Output GEMM: out[4096,1024] = valsh @ woh^T + bo, fp32 out. K = 1024.
// 64x128 tile, BK=64, single-buffered 24 KB LDS, 2-barrier loop, swizzled.
// ---------------------------------------------------------------------------
__global__ __launch_bounds__(256) void gemm_out(const u16* __restrict__ A,
                                                const u16* __restrict__ B,
                                                const float* __restrict__ bo,
                                                float* __restrict__ out)
{
    __shared__ __align__(16) u16 As[64][64];     // 8 KB
    __shared__ __align__(16) u16 Bs[128][64];    // 16 KB

    const int tid  = threadIdx.x;
    const int lane = tid & 63, wid = tid >> 6;
    const int wm = wid >> 1, wn = wid & 1;
    const int swz = (blockIdx.x & 7) * 64 + (blockIdx.x >> 3);   // 512 blocks
    const int m0 = (swz & 63) * 64;
    const int n0 = (swz >> 6) * 128;

    size_t aoff[2], boff[4];
    #pragma unroll
    for (int i = 0; i < 2; ++i) {
        const int flat = i * 256 + tid;
        const int row = flat >> 3, u = flat & 7;
        aoff[i] = (size_t)row * 2048 + ((u ^ (row & 7)) << 4);
    }
    #pragma unroll
    for (int i = 0; i < 4; ++i) {
        const int flat = i * 256 + tid;
        const int row = flat >> 3, u = flat & 7;
        boff[i] = (size_t)row * 2048 + ((u ^ (row & 7)) << 4);
    }
    const char* Abase = (const char*)(A + (size_t)m0 * 1024);
    const char* Bbase = (const char*)(B + (size_t)n0 * 1024);

    f32x4 acc[2][4];
    #pragma unroll
    for (int i = 0; i < 2; ++i)
        #pragma unroll
        for (int j = 0; j < 4; ++j) acc[i][j] = f32x4{0.f, 0.f, 0.f, 0.f};

    #pragma unroll 1
    for (int t = 0; t < 16; ++t) {
        const size_t kb_ = (size_t)t * 128;
        #pragma unroll
        for (int i = 0; i < 2; ++i)
            gload16(Abase + aoff[i] + kb_, (char*)As + (i * 256 + wid * 64) * 16);
        #pragma unroll
        for (int i = 0; i < 4; ++i)
            gload16(Bbase + boff[i] + kb_, (char*)Bs + (i * 256 + wid * 64) * 16);
        __syncthreads();

        #pragma unroll
        for (int kk = 0; kk < 2; ++kk) {
            s16x8 af[2], bfr[4];
            #pragma unroll
            for (int i = 0; i < 2; ++i) {
                const int rowA = wm * 32 + i * 16 + (lane & 15);
                af[i] = *(const s16x8*)((const char*)As + rowA * 128 + (((kk * 4 + (lane >> 4)) ^ (rowA & 7)) << 4));
            }
            #pragma unroll
            for (int j = 0; j < 4; ++j) {
                const int rowB = wn * 64 + j * 16 + (lane & 15);
                bfr[j] = *(const s16x8*)((const char*)Bs + rowB * 128 + (((kk * 4 + (lane >> 4)) ^ (rowB & 7)) << 4));
            }
            #pragma unroll
            for (int i = 0; i < 2; ++i)
                #pragma unroll
                for (int j = 0; j < 4; ++j)
                    acc[i][j] = __builtin_amdgcn_mfma_f32_16x16x32_bf16(af[i], bfr[j], acc[i][j], 0, 0, 0);
        }
        __syncthreads();
    }

    #pragma unroll
    for (int i = 0; i < 2; ++i) {
        const int mbase = m0 + wm * 32 + i * 16 + ((lane >> 4) * 4);
        #pragma unroll
        for (int j = 0; j < 4; ++j) {
            const int n = n0 + wn * 64 + j * 16 + (lane & 15);
            #pragma unroll
            for (int r = 0; r < 4; ++r)
                out[(size_t)(mbase + r) * EDIM + n] = acc[i][j][r] + bo[n];
        }
    }
}

// ---------------------------------------------------------------------------
// MFMA flash attention, swapped-QK^T, in-register softmax (T12).
// ROUND 11: SINGLE-buffered K/V (32 KB LDS -> ~5 blocks/CU, was 2 with dbuf;
// the 17% occupancy was the limiter, and bank conflicts measured ~1% of
// runtime — accepted). Per-lane staging pointers bump by constants per chunk
// (no per-chunk address math). Softmax scale pre-folded into Q (QSCALE at
// projection) -> P = exp2(S) directly. setprio restored (r9 config).
// ---------------------------------------------------------------------------
__global__ __launch_bounds__(256) void attn_mfma(const u16* __restrict__ q,
                                                 const u16* __restrict__ k,
                                                 const u16* __restrict__ vT,
                                                 u16* __restrict__ valsh)
{
    __shared__ __align__(16) u16 kt[128][64];    // 16 KB
    __shared__ __align__(16) u16 vt[64][128];    // 16 KB

    const int tid = threadIdx.x, lane = tid & 63, wid = tid >> 6;
    const int lq = lane & 31, hi = lane >> 5;
    const int swz = (blockIdx.x & 7) * 64 + (blockIdx.x >> 3);   // 512 blocks
    const int bh = swz >> 4, qt = swz & 15;
    const int b = bh >> 4, h = bh & 15;

    // ---- Q B-frags straight from global (L2-resident, one-time) ----
    const u16* qg = q + ((size_t)bh * SS + qt * 128 + wid * 32 + lq) * DH + hi * 8;
    s16x8 qf[4];
    #pragma unroll
    for (int ks = 0; ks < 4; ++ks) qf[ks] = *(const s16x8*)(qg + ks * 16);

    f32x16 acc_o[2];
    #pragma unroll
    for (int db = 0; db < 2; ++db)
        #pragma unroll
        for (int r = 0; r < 16; ++r) acc_o[db][r] = 0.f;
    float rs = 0.f;

    // ---- per-lane staging source pointers (bump by constants per chunk) ----
    const char* kbh = (const char*)(k + (size_t)bh * SS * DH);
    const char* vbh = (const char*)(vT + ((size_t)b * EDIM + h * DH) * SS);
    const char* ksrc[4]; const char* vsrc[4];
    #pragma unroll
    for (int i = 0; i < 4; ++i) {
        const int flat = i * 256 + tid;
        const int row = flat >> 3, u = flat & 7;
        const int su = u ^ (row & 7) ^ ((row >> 3) & 3);
        ksrc[i] = kbh + (size_t)row * 128 + (su << 4);
        const int rowv = flat >> 4, uv = flat & 15;
        const int suv = uv ^ (rowv & 15) ^ ((rowv & 16) >> 2);
        vsrc[i] = vbh + (size_t)rowv * (SS * 2) + (suv << 4);
    }

    #pragma unroll 1
    for (int c = 0; c < 16; ++c) {
        // ---- stage this chunk (latency hidden by co-resident blocks) ----
        #pragma unroll
        for (int i = 0; i < 4; ++i) {
            gload16(ksrc[i], (char*)kt + (i * 256 + wid * 64) * 16);
            ksrc[i] += 128 * 128;          // next 128 K-rows
        }
        #pragma unroll
        for (int i = 0; i < 4; ++i) {
            gload16(vsrc[i], (char*)vt + (i * 256 + wid * 64) * 16);
            vsrc[i] += 256;                // next 128 keys within the row
        }
        __syncthreads();   // staged data visible

        #pragma unroll
        for (int kb = 0; kb < 4; ++kb) {
            // ---- S^T = K @ Q' over d (Q' carries log2(e)/64) ----
            f32x16 sc;
            #pragma unroll
            for (int r = 0; r < 16; ++r) sc[r] = 0.f;
            const int krow = kb * 32 + lq;
            __builtin_amdgcn_s_setprio(1);
            #pragma unroll
            for (int ks = 0; ks < 4; ++ks) {
                const int u = (ks * 2 + hi) ^ (krow & 7) ^ ((krow >> 3) & 3);
                const s16x8 kf = *(const s16x8*)((const char*)kt + krow * 128 + u * 16);
                sc = __builtin_amdgcn_mfma_f32_32x32x16_bf16(kf, qf[ks], sc, 0, 0, 0);
            }
            __builtin_amdgcn_s_setprio(0);

            // ---- P = exp2(S) in-register; accumulate rowsum ----
            #pragma unroll
            for (int r = 0; r < 16; ++r) {
                sc[r] = __builtin_amdgcn_exp2f(sc[r]);
                rs += sc[r];
            }

            // ---- pack to PV A-frags: cvt_pk pairs + permlane32_swap ----
            u32 w0 = cvtpk(sc[0],  sc[1]),  w1 = cvtpk(sc[2],  sc[3]);
            u32 w2 = cvtpk(sc[4],  sc[5]),  w3 = cvtpk(sc[6],  sc[7]);
            u32 w4 = cvtpk(sc[8],  sc[9]),  w5 = cvtpk(sc[10], sc[11]);
            u32 w6 = cvtpk(sc[12], sc[13]), w7 = cvtpk(sc[14], sc[15]);
            swap32(w0, w2);
            swap32(w1, w3);
            swap32(w4, w6);
            swap32(w5, w7);
            union { u32 w[4]; s16x8 v; } pa0, pa1;
            pa0.w[0] = w0; pa0.w[1] = w1; pa0.w[2] = w2; pa0.w[3] = w3;
            pa1.w[0] = w4; pa1.w[1] = w5; pa1.w[2] = w6; pa1.w[3] = w7;

            // ---- O += P @ V : A = P frags (reg), B = V^T rows from LDS ----
            __builtin_amdgcn_s_setprio(1);
            #pragma unroll
            for (int t = 0; t < 2; ++t) {
                const s16x8 pat = t ? pa1.v : pa0.v;
                const int kst = kb * 2 + t;
                #pragma unroll
                for (int db = 0; db < 2; ++db) {
                    const int vrow = db * 32 + lq;
                    const int u = (kst * 2 + hi) ^ (vrow & 15) ^ ((vrow & 16) >> 2);
                    const s16x8 vf = *(const s16x8*)((const char*)vt + vrow * 256 + u * 16);
                    acc_o[db] = __builtin_amdgcn_mfma_f32_32x32x16_bf16(pat, vf, acc_o[db], 0, 0, 0);
                }
            }
            __builtin_amdgcn_s_setprio(0);
        }
        __syncthreads();   // this chunk's LDS reads done before next stage
    }

    // ---- rowsum: lane l and l^32 hold complementary key sets of q=lq ----
    const float rsf = rs + __shfl_xor(rs, 32, 64);
    const float inv = 1.f / rsf;
    float iv[16];
    #pragma unroll
    for (int r = 0; r < 16; ++r)
        iv[r] = __shfl(inv, (r & 3) + 8 * (r >> 2) + 4 * hi, 64);

    // ---- epilogue: normalize + write bf16 vals [B*S][E] ----
    #pragma unroll
    for (int db = 0; db < 2; ++db)
        #pragma unroll
        for (int r = 0; r < 16; ++r) {
            const int srow = qt * 128 + wid * 32 + (r & 3) + 8 * (r >> 2) + 4 * hi;
            const int col  = h * 64 + db * 32 + lq;
            valsh[(size_t)(b * SS + srow) * EDIM + col] = f2bf(acc_o[db][r] * iv[r]);
        }
}

// ---------------------------------------------------------------------------
extern "C" void kernel_launch(void* const* d_in, const int* in_sizes, int n_in,
                              void* d_out, int out_size, void* d_ws, size_t ws_size,
                              hipStream_t stream)
{
    const float* x  = (const float*)d_in[0];
    const float* Wq = (const float*)d_in[1];
    const float* bq = (const float*)d_in[2];
    const float* Wk = (const float*)d_in[3];
    const float* bk = (const float*)d_in[4];
    const float* Wv = (const float*)d_in[5];
    const float* bv = (const float*)d_in[6];
    const float* Wo = (const float*)d_in[7];
    const float* bo = (const float*)d_in[8];
    float* out = (float*)d_out;

    u16* W = (u16*)d_ws;
    const size_t M1 = 1024 * 1024;
    u16* xh    = W;                 // [4096][1024]        4M elems
    u16* wqkv  = W + 4  * M1;       // [3072][1024]        3M
    u16* woh   = W + 7  * M1;       // [1024][1024]        1M
    u16* qbuf  = W + 8  * M1;       // [BH][S][64]         4M
    u16* kbuf  = W + 12 * M1;       // [BH][S][64]         4M
    u16* vbufT = W + 16 * M1;       // [B*1024][S]         4M
    u16* valsh = W + 20 * M1;       // [4096][1024]        4M

    convert_all<<<dim3(8192), 256, 0, stream>>>(x, Wq, Wk, Wv, Wo, xh, wqkv, woh);

    gemm_qkv<<<dim3(768), 256, 0, stream>>>(xh, wqkv, bq, bk, bv, qbuf, kbuf, vbufT);

    attn_mfma<<<dim3(BB * NH * (SS / 128)), 256, 0, stream>>>(qbuf, kbuf, vbufT, valsh);

    gemm_out<<<dim3(512), 256, 0, stream>>>(valsh, woh, bo, out);
}